// Round 2
// baseline (591.083 us; speedup 1.0000x reference)
//
#include <hip/hip_runtime.h>
#include <math.h>

#define D 64
#define K 512
#define TILE_ROWS 256   // 256 rows * 64 floats * 4 B = 64 KB LDS tile

// ---------------------------------------------------------------------------
// numpy pairwise sum of v[i]*v[i], n=64 — exact numpy algorithm:
//   p[i] = v[i]*v[i] (rounded, NO fma)
//   r[j] = p[j]; for b=8..56 step 8: r[j] += p[b+j]
//   res = ((r0+r1)+(r2+r3)) + ((r4+r5)+(r6+r7))
// ---------------------------------------------------------------------------
__device__ __forceinline__ float np_sumsq64(const float* v)
{
#pragma clang fp contract(off)
    float p[64];
#pragma unroll
    for (int i = 0; i < 64; ++i) p[i] = v[i] * v[i];
    float r[8];
#pragma unroll
    for (int j = 0; j < 8; ++j) r[j] = p[j];
#pragma unroll
    for (int b = 8; b < 64; b += 8) {
#pragma unroll
        for (int j = 0; j < 8; ++j) r[j] += p[b + j];
    }
    return ((r[0] + r[1]) + (r[2] + r[3])) + ((r[4] + r[5]) + (r[6] + r[7]));
}

// ---------------------------------------------------------------------------
// Kernel 1: e2[k] = numpy-f32 sum(e_k*e_k); sq[k] = f32 sqrt(cs[k])
// ---------------------------------------------------------------------------
__global__ void vq_prep(const float* __restrict__ emb,
                        const float* __restrict__ cs,
                        float* __restrict__ e2,
                        float* __restrict__ sq)
{
    int k = blockIdx.x * blockDim.x + threadIdx.x;
    if (k >= K) return;
    float er[64];
    const float* ek = emb + (size_t)k * D;
#pragma unroll
    for (int d = 0; d < 64; ++d) er[d] = ek[d];
    e2[k] = np_sumsq64(er);
    // binary32 sqrt via binary64 is exactly the correctly-rounded f32 sqrt
    sq[k] = (float)sqrt((double)cs[k]);
}

// ---------------------------------------------------------------------------
// Kernel 2: argmin over K codes, mimicking numpy float32 semantics exactly.
// dot = single ascending-k fmaf chain from 0 (sgemm microkernel order);
// dist = ((x2 + e2[j]) - 2.0f*dot) * sq[j], every op rounded f32;
// strict < ascending j = first-index-wins argmin.
// One thread per point; codebook staged in LDS in two 64 KB tiles
// (all lanes read the same LDS address -> broadcast, conflict-free).
// ---------------------------------------------------------------------------
__global__ __launch_bounds__(256) void vq_argmin(
    const float* __restrict__ x,
    const float* __restrict__ emb,
    const float* __restrict__ e2,
    const float* __restrict__ sq,
    float* __restrict__ out_idx,
    int N)
{
    __shared__ float se[TILE_ROWS * D];   // 64 KB

    int n = blockIdx.x * blockDim.x + threadIdx.x;

    float xr[64];
    if (n < N) {
        const float4* xp = (const float4*)(x + (size_t)n * D);
#pragma unroll
        for (int t = 0; t < 16; ++t) {
            float4 v = xp[t];
            xr[4 * t + 0] = v.x;
            xr[4 * t + 1] = v.y;
            xr[4 * t + 2] = v.z;
            xr[4 * t + 3] = v.w;
        }
    } else {
#pragma unroll
        for (int i = 0; i < 64; ++i) xr[i] = 0.0f;
    }
    float x2 = np_sumsq64(xr);

    float best = INFINITY;
    int bi = 0;

    for (int t = 0; t < K / TILE_ROWS; ++t) {
        __syncthreads();
        {
            const float4* src = (const float4*)(emb + (size_t)t * TILE_ROWS * D);
            float4* dst = (float4*)se;
            for (int i = threadIdx.x; i < TILE_ROWS * D / 4; i += 256)
                dst[i] = src[i];
        }
        __syncthreads();

        for (int j = 0; j < TILE_ROWS; j += 4) {
            const float* r0 = se + j * D;
            float a0 = 0.0f, a1 = 0.0f, a2 = 0.0f, a3 = 0.0f;
#pragma unroll
            for (int k = 0; k < 64; k += 4) {
                float4 v0 = *(const float4*)(r0 + k);
                float4 v1 = *(const float4*)(r0 + D + k);
                float4 v2 = *(const float4*)(r0 + 2 * D + k);
                float4 v3 = *(const float4*)(r0 + 3 * D + k);
                a0 = fmaf(xr[k + 0], v0.x, a0);
                a0 = fmaf(xr[k + 1], v0.y, a0);
                a0 = fmaf(xr[k + 2], v0.z, a0);
                a0 = fmaf(xr[k + 3], v0.w, a0);
                a1 = fmaf(xr[k + 0], v1.x, a1);
                a1 = fmaf(xr[k + 1], v1.y, a1);
                a1 = fmaf(xr[k + 2], v1.z, a1);
                a1 = fmaf(xr[k + 3], v1.w, a1);
                a2 = fmaf(xr[k + 0], v2.x, a2);
                a2 = fmaf(xr[k + 1], v2.y, a2);
                a2 = fmaf(xr[k + 2], v2.z, a2);
                a2 = fmaf(xr[k + 3], v2.w, a2);
                a3 = fmaf(xr[k + 0], v3.x, a3);
                a3 = fmaf(xr[k + 1], v3.y, a3);
                a3 = fmaf(xr[k + 2], v3.z, a3);
                a3 = fmaf(xr[k + 3], v3.w, a3);
            }
            int jg = t * TILE_ROWS + j;
            {
#pragma clang fp contract(off)
                float d0 = ((x2 + e2[jg + 0]) - 2.0f * a0) * sq[jg + 0];
                float d1 = ((x2 + e2[jg + 1]) - 2.0f * a1) * sq[jg + 1];
                float d2 = ((x2 + e2[jg + 2]) - 2.0f * a2) * sq[jg + 2];
                float d3 = ((x2 + e2[jg + 3]) - 2.0f * a3) * sq[jg + 3];
                if (d0 < best) { best = d0; bi = jg + 0; }
                if (d1 < best) { best = d1; bi = jg + 1; }
                if (d2 < best) { best = d2; bi = jg + 2; }
                if (d3 < best) { best = d3; bi = jg + 3; }
            }
        }
    }
    if (n < N) out_idx[n] = (float)bi;
}

// ---------------------------------------------------------------------------
// Kernel 3: gather chosen code, STE output, fp64 per-block loss partials
// ---------------------------------------------------------------------------
__global__ __launch_bounds__(256) void vq_epilogue(
    const float* __restrict__ x,
    const float* __restrict__ emb,
    const float* __restrict__ idx_f,
    float* __restrict__ out_q,
    double* __restrict__ partial)
{
    int i = blockIdx.x * blockDim.x + threadIdx.x;   // float4 index
    int n  = i >> 4;
    int d4 = i & 15;

    int bi = (int)idx_f[n];
    float4 q4 = *(const float4*)(emb + (size_t)bi * D + 4 * d4);
    float4 x4 = ((const float4*)x)[i];

    float4 o;
    o.x = x4.x + (q4.x - x4.x);
    o.y = x4.y + (q4.y - x4.y);
    o.z = x4.z + (q4.z - x4.z);
    o.w = x4.w + (q4.w - x4.w);
    ((float4*)out_q)[i] = o;

    double dx = (double)q4.x - (double)x4.x;
    double dy = (double)q4.y - (double)x4.y;
    double dz = (double)q4.z - (double)x4.z;
    double dw = (double)q4.w - (double)x4.w;
    double s = dx * dx + dy * dy + dz * dz + dw * dw;

#pragma unroll
    for (int off = 32; off > 0; off >>= 1)
        s += __shfl_down(s, off, 64);

    __shared__ double ls[4];
    if ((threadIdx.x & 63) == 0) ls[threadIdx.x >> 6] = s;
    __syncthreads();
    if (threadIdx.x == 0)
        partial[blockIdx.x] = ls[0] + ls[1] + ls[2] + ls[3];
}

// ---------------------------------------------------------------------------
// Kernel 4: reduce partials -> loss
// ---------------------------------------------------------------------------
__global__ __launch_bounds__(256) void vq_finalize(
    const double* __restrict__ partial,
    float* __restrict__ loss_out,
    int nblk, double inv_count)
{
    double s = 0.0;
    for (int i = threadIdx.x; i < nblk; i += 256) s += partial[i];
#pragma unroll
    for (int off = 32; off > 0; off >>= 1)
        s += __shfl_down(s, off, 64);
    __shared__ double ls[4];
    if ((threadIdx.x & 63) == 0) ls[threadIdx.x >> 6] = s;
    __syncthreads();
    if (threadIdx.x == 0) {
        double total = ls[0] + ls[1] + ls[2] + ls[3];
        loss_out[0] = (float)(0.25 * total * inv_count);
    }
}

// ---------------------------------------------------------------------------
extern "C" void kernel_launch(void* const* d_in, const int* in_sizes, int n_in,
                              void* d_out, int out_size, void* d_ws, size_t ws_size,
                              hipStream_t stream)
{
    const float* x   = (const float*)d_in[0];   // [N, 64]
    const float* emb = (const float*)d_in[1];   // [512, 64]
    const float* cs  = (const float*)d_in[2];   // [512]

    const int N = in_sizes[0] / D;              // 262144

    float* out      = (float*)d_out;
    float* out_q    = out;                      // [N*64]
    float* out_loss = out + (size_t)N * D;      // [1]
    float* out_idx  = out_loss + 1;             // [N]

    // workspace layout
    float*  e2      = (float*)d_ws;                       // 512 f32
    float*  sq      = e2 + K;                             // 512 f32
    double* partial = (double*)((char*)d_ws + 8192);      // 16384 f64

    const int nblk_ep = (N * D / 4) / 256;      // 16384

    vq_prep<<<(K + 255) / 256, 256, 0, stream>>>(emb, cs, e2, sq);
    vq_argmin<<<(N + 255) / 256, 256, 0, stream>>>(x, emb, e2, sq, out_idx, N);
    vq_epilogue<<<nblk_ep, 256, 0, stream>>>(x, emb, out_idx, out_q, partial);
    vq_finalize<<<1, 256, 0, stream>>>(partial, out_loss, nblk_ep,
                                       1.0 / ((double)N * (double)D));
}